// Round 5
// baseline (1947.293 us; speedup 1.0000x reference)
//
#include <hip/hip_runtime.h>

#define N_NODES 50000
#define N_EDGES 800000
#define D 64
#define NUM_GRAPHS 512
#define FINAL_NEURON 128
#define SCAN_NB ((N_NODES + 255) / 256)   // 196 blocks

// ---------------- CSR build ----------------
__global__ void k_zero2(int* a, int* b, int n) {
    int i = blockIdx.x * blockDim.x + threadIdx.x;
    if (i < n) { a[i] = 0; b[i] = 0; }
}

__global__ void k_hist(const int* __restrict__ dst, int* cnt) {
    int e = blockIdx.x * blockDim.x + threadIdx.x;
    if (e < N_EDGES) atomicAdd(&cnt[dst[e]], 1);
}

// per-block sums of cnt; also emit dinv = rsqrt(cnt+1)
__global__ void k_blocksum(const int* __restrict__ cnt, int* __restrict__ bsum,
                           float* __restrict__ dinv) {
    __shared__ int sdata[256];
    int t = threadIdx.x;
    int i = blockIdx.x * 256 + t;
    int v = (i < N_NODES) ? cnt[i] : 0;
    if (i < N_NODES) dinv[i] = rsqrtf((float)v + 1.0f);
    sdata[t] = v;
    __syncthreads();
    for (int s = 128; s > 0; s >>= 1) {
        if (t < s) sdata[t] += sdata[t + s];
        __syncthreads();
    }
    if (t == 0) bsum[blockIdx.x] = sdata[0];
}

// single-block exclusive scan of block sums
__global__ void k_scanbsum(const int* __restrict__ bsum, int* __restrict__ boff) {
    __shared__ int buf[256];
    int t = threadIdx.x;
    int v = (t < SCAN_NB) ? bsum[t] : 0;
    buf[t] = v;
    __syncthreads();
    for (int off = 1; off < 256; off <<= 1) {
        int a = (t >= off) ? buf[t - off] : 0;
        __syncthreads();
        buf[t] += a;
        __syncthreads();
    }
    if (t < SCAN_NB) boff[t] = buf[t] - v;   // exclusive
}

// local exclusive scan + block offset -> row
__global__ void k_localscan(const int* __restrict__ cnt, const int* __restrict__ boff,
                            int* __restrict__ row) {
    __shared__ int buf[256];
    int t = threadIdx.x;
    int i = blockIdx.x * 256 + t;
    int v = (i < N_NODES) ? cnt[i] : 0;
    buf[t] = v;
    __syncthreads();
    for (int off = 1; off < 256; off <<= 1) {
        int a = (t >= off) ? buf[t - off] : 0;
        __syncthreads();
        buf[t] += a;
        __syncthreads();
    }
    if (i < N_NODES) row[i] = boff[blockIdx.x] + buf[t] - v;
    if (i == 0) row[N_NODES] = N_EDGES;
}

// place each edge: one packed 8B store {src, norm}.
// Blocks sweep dst ranges with blockIdx%8 == range, matching the round-robin
// block->XCD dispatch so each XCD's L2 only dirties its own 1/8 of `edge`.
// Correctness does NOT depend on the mapping; it's a locality heuristic.
#define FILL_GROUP_BLOCKS 392
__global__ void k_fill(const int* __restrict__ src, const int* __restrict__ dst,
                       const int* __restrict__ row, int* cur,
                       const float* __restrict__ dinv,
                       int2* __restrict__ edge) {
    int rng = blockIdx.x & 7;
    int lo = rng * (N_NODES / 8);
    int hi = (rng == 7) ? N_NODES : lo + (N_NODES / 8);
    int stride = FILL_GROUP_BLOCKS * 256;
    for (int e = (blockIdx.x >> 3) * 256 + threadIdx.x; e < N_EDGES; e += stride) {
        int d = dst[e];
        if (d < lo || d >= hi) continue;
        int s = src[e];
        int pos = atomicAdd(&cur[d], 1);
        float nm = dinv[s] * dinv[d];
        int2 packed = {s, __float_as_int(nm)};
        edge[row[d] + pos] = packed;
    }
}

// ---------------- per-layer GEMM: hw = h @ W ----------------
// 256 threads; block = 64 rows. Thread t: col-group c = t&15 (float4), rows
// rt..rt+3 with rt = (t>>4)*4. 4 rows/thread amortizes the LDS W reads 4x.
__global__ void k_gemm(const float* __restrict__ h, const float* __restrict__ W,
                       float* __restrict__ hw) {
    __shared__ float4 Ws4[D * 16];       // 16 KB
    __shared__ float  hs[64 * 68];       // 17.4 KB, padded stride 68 (16B-aligned)
    int t = threadIdx.x;
    int c = t & 15;
    int rt = (t >> 4) * 4;
    int base = blockIdx.x * 64;

    const float4* W4 = (const float4*)W;
    #pragma unroll
    for (int idx = t; idx < D * 16; idx += 256) Ws4[idx] = W4[idx];
    #pragma unroll
    for (int i = t; i < 64 * 16; i += 256) {
        int r = i >> 4, cc = i & 15;
        if (base + r < N_NODES)
            *(float4*)&hs[r * 68 + cc * 4] = ((const float4*)h)[(size_t)(base + r) * 16 + cc];
    }
    __syncthreads();

    float4 acc0 = {0,0,0,0}, acc1 = {0,0,0,0}, acc2 = {0,0,0,0}, acc3 = {0,0,0,0};
    #pragma unroll
    for (int kk = 0; kk < 16; ++kk) {
        float4 w0 = Ws4[(kk * 4 + 0) * 16 + c];
        float4 w1 = Ws4[(kk * 4 + 1) * 16 + c];
        float4 w2 = Ws4[(kk * 4 + 2) * 16 + c];
        float4 w3 = Ws4[(kk * 4 + 3) * 16 + c];
        #define GEMM_ROW(ACC, RR) { \
            float4 hv = *(const float4*)&hs[(rt + RR) * 68 + kk * 4]; \
            ACC.x += hv.x * w0.x + hv.y * w1.x + hv.z * w2.x + hv.w * w3.x; \
            ACC.y += hv.x * w0.y + hv.y * w1.y + hv.z * w2.y + hv.w * w3.y; \
            ACC.z += hv.x * w0.z + hv.y * w1.z + hv.z * w2.z + hv.w * w3.z; \
            ACC.w += hv.x * w0.w + hv.y * w1.w + hv.z * w2.w + hv.w * w3.w; }
        GEMM_ROW(acc0, 0) GEMM_ROW(acc1, 1) GEMM_ROW(acc2, 2) GEMM_ROW(acc3, 3)
        #undef GEMM_ROW
    }
    if (base + rt + 0 < N_NODES) ((float4*)hw)[(size_t)(base + rt + 0) * 16 + c] = acc0;
    if (base + rt + 1 < N_NODES) ((float4*)hw)[(size_t)(base + rt + 1) * 16 + c] = acc1;
    if (base + rt + 2 < N_NODES) ((float4*)hw)[(size_t)(base + rt + 2) * 16 + c] = acc2;
    if (base + rt + 3 < N_NODES) ((float4*)hw)[(size_t)(base + rt + 3) * 16 + c] = acc3;
}

// ---------------- CSR aggregate + self-loop + bias + relu ----------------
// 256 threads = 4 waves; wave = 1 node; 8 edge-subgroups x 8 lanes; each lane
// covers 2 float4 column-groups -> 16 outstanding loads per wave.
__global__ void k_aggregate(const int* __restrict__ row, const int2* __restrict__ edge,
                            const float* __restrict__ hw,
                            const float* __restrict__ dinv, const float* __restrict__ b,
                            float* __restrict__ hout) {
    int t = threadIdx.x;
    int w = t >> 6;
    int l = t & 63;
    int n = blockIdx.x * 4 + w;
    if (n >= N_NODES) return;
    int sub = l >> 3;        // 0..7: edge slot
    int c = l & 7;           // float4 col group (first half)

    const float4* hw4 = (const float4*)hw;
    float4 acc0 = {0.f, 0.f, 0.f, 0.f};
    float4 acc1 = {0.f, 0.f, 0.f, 0.f};
    int e0 = row[n], e1 = row[n + 1];
    for (int e = e0 + sub; e < e1; e += 8) {
        int2 ed = edge[e];
        int s = ed.x;
        float nm = __int_as_float(ed.y);
        float4 v0 = hw4[(size_t)s * 16 + c];
        float4 v1 = hw4[(size_t)s * 16 + c + 8];
        acc0.x += v0.x * nm; acc0.y += v0.y * nm; acc0.z += v0.z * nm; acc0.w += v0.w * nm;
        acc1.x += v1.x * nm; acc1.y += v1.y * nm; acc1.z += v1.z * nm; acc1.w += v1.w * nm;
    }
    if (sub == 0) {          // self-loop, exactly once
        float di = dinv[n];
        float sc = di * di;
        float4 v0 = hw4[(size_t)n * 16 + c];
        float4 v1 = hw4[(size_t)n * 16 + c + 8];
        acc0.x += v0.x * sc; acc0.y += v0.y * sc; acc0.z += v0.z * sc; acc0.w += v0.w * sc;
        acc1.x += v1.x * sc; acc1.y += v1.y * sc; acc1.z += v1.z * sc; acc1.w += v1.w * sc;
    }
    #pragma unroll
    for (int m = 8; m < 64; m <<= 1) {
        acc0.x += __shfl_xor(acc0.x, m); acc0.y += __shfl_xor(acc0.y, m);
        acc0.z += __shfl_xor(acc0.z, m); acc0.w += __shfl_xor(acc0.w, m);
        acc1.x += __shfl_xor(acc1.x, m); acc1.y += __shfl_xor(acc1.y, m);
        acc1.z += __shfl_xor(acc1.z, m); acc1.w += __shfl_xor(acc1.w, m);
    }

    if (sub == 0) {
        float4 b0 = ((const float4*)b)[c];
        float4 b1 = ((const float4*)b)[c + 8];
        float4 r0, r1;
        r0.x = fmaxf(acc0.x + b0.x, 0.f); r0.y = fmaxf(acc0.y + b0.y, 0.f);
        r0.z = fmaxf(acc0.z + b0.z, 0.f); r0.w = fmaxf(acc0.w + b0.w, 0.f);
        r1.x = fmaxf(acc1.x + b1.x, 0.f); r1.y = fmaxf(acc1.y + b1.y, 0.f);
        r1.z = fmaxf(acc1.z + b1.z, 0.f); r1.w = fmaxf(acc1.w + b1.w, 0.f);
        ((float4*)hout)[(size_t)n * 16 + c] = r0;
        ((float4*)hout)[(size_t)n * 16 + c + 8] = r1;
    }
}

// ---------------- pooling ----------------
__global__ void k_zero_g(float* g) {
    int i = blockIdx.x * blockDim.x + threadIdx.x;
    if (i < NUM_GRAPHS * D) g[i] = 0.f;
}

__global__ void k_pool(const int* __restrict__ batch, const float* __restrict__ h,
                       float* g) {
    int tid = blockIdx.x * blockDim.x + threadIdx.x;
    int f = tid & 63;
    int n0 = (tid >> 6) * 8;
    if (n0 >= N_NODES) return;
    int n1 = n0 + 8; if (n1 > N_NODES) n1 = N_NODES;
    int curb = batch[n0];
    float acc = 0.f;
    for (int n = n0; n < n1; ++n) {
        int bb = batch[n];
        if (bb != curb) { atomicAdd(&g[curb * D + f], acc); acc = 0.f; curb = bb; }
        acc += h[(size_t)n * D + f];
    }
    atomicAdd(&g[curb * D + f], acc);
}

// ---------------- fc1 ----------------
__global__ void k_fc1(const float* __restrict__ g, const float* __restrict__ W,
                      const float* __restrict__ b, float* __restrict__ g2) {
    int row = blockIdx.x;
    int j = threadIdx.x;
    float acc = 0.f;
    #pragma unroll
    for (int k = 0; k < D; ++k) acc += g[row * D + k] * W[k * FINAL_NEURON + j];
    acc += b[j];
    g2[row * FINAL_NEURON + j] = acc > 0.f ? acc : 0.f;
}

// ---------------- fc2 ----------------
__global__ void k_fc2(const float* __restrict__ g2, const float* __restrict__ W,
                      const float* __restrict__ b, float* __restrict__ out) {
    int row = blockIdx.x * blockDim.x + threadIdx.x;
    if (row >= NUM_GRAPHS) return;
    float acc = b[0];
    #pragma unroll
    for (int k = 0; k < FINAL_NEURON; ++k) acc += g2[row * FINAL_NEURON + k] * W[k];
    out[row] = acc;
}

extern "C" void kernel_launch(void* const* d_in, const int* in_sizes, int n_in,
                              void* d_out, int out_size, void* d_ws, size_t ws_size,
                              hipStream_t stream) {
    const float* x     = (const float*)d_in[0];
    const int*   ei    = (const int*)d_in[1];
    const int*   src   = ei;
    const int*   dst   = ei + N_EDGES;
    const int*   batch = (const int*)d_in[2];
    const float* W[5]  = {(const float*)d_in[3], (const float*)d_in[5], (const float*)d_in[7],
                          (const float*)d_in[9], (const float*)d_in[11]};
    const float* b[5]  = {(const float*)d_in[4], (const float*)d_in[6], (const float*)d_in[8],
                          (const float*)d_in[10], (const float*)d_in[12]};
    const float* fc1W  = (const float*)d_in[13];
    const float* fc1b  = (const float*)d_in[14];
    const float* fc2W  = (const float*)d_in[15];
    const float* fc2b  = (const float*)d_in[16];
    float* out = (float*)d_out;

    int2*  edge  = (int2*)d_ws;                     // E int2
    float* dinv  = (float*)(edge + N_EDGES);        // N
    int*   cnt   = (int*)(dinv + N_NODES);          // N
    int*   row   = cnt + N_NODES;                   // N+1
    int*   cur   = row + N_NODES + 1;               // N
    int*   bsum  = cur + N_NODES;                   // 256
    int*   boff  = bsum + 256;                      // 256
    float* hbuf  = (float*)(boff + 256);            // N*D
    float* hw    = hbuf + (size_t)N_NODES * D;      // N*D
    float* g     = hw + (size_t)N_NODES * D;        // G*D
    float* g2    = g + NUM_GRAPHS * D;              // G*128

    // ---- CSR build ----
    k_zero2<<<(N_NODES + 255) / 256, 256, 0, stream>>>(cnt, cur, N_NODES);
    k_hist<<<(N_EDGES + 255) / 256, 256, 0, stream>>>(dst, cnt);
    k_blocksum<<<SCAN_NB, 256, 0, stream>>>(cnt, bsum, dinv);
    k_scanbsum<<<1, 256, 0, stream>>>(bsum, boff);
    k_localscan<<<SCAN_NB, 256, 0, stream>>>(cnt, boff, row);
    k_fill<<<FILL_GROUP_BLOCKS * 8, 256, 0, stream>>>(src, dst, row, cur, dinv, edge);

    // ---- 5 GCN layers ----
    const float* hin = x;
    for (int L = 0; L < 5; ++L) {
        k_gemm<<<(N_NODES + 63) / 64, 256, 0, stream>>>(hin, W[L], hw);
        k_aggregate<<<(N_NODES + 3) / 4, 256, 0, stream>>>(row, edge, hw, dinv, b[L], hbuf);
        hin = hbuf;
    }

    // ---- readout + MLP ----
    k_zero_g<<<(NUM_GRAPHS * D + 255) / 256, 256, 0, stream>>>(g);
    k_pool<<<((N_NODES + 7) / 8 * 64 + 255) / 256, 256, 0, stream>>>(batch, hbuf, g);
    k_fc1<<<NUM_GRAPHS, FINAL_NEURON, 0, stream>>>(g, fc1W, fc1b, g2);
    k_fc2<<<(NUM_GRAPHS + 255) / 256, 256, 0, stream>>>(g2, fc2W, fc2b, out);
}

// Round 6
// 431.834 us; speedup vs baseline: 4.5094x; 4.5094x over previous
//
#include <hip/hip_runtime.h>

#define N_NODES 50000
#define N_EDGES 800000
#define D 64
#define NUM_GRAPHS 512
#define FINAL_NEURON 128
#define SCAN_NB ((N_NODES + 255) / 256)   // 196 blocks

// ---------------- CSR build ----------------
__global__ void k_zero2(int* a, int* b, int n) {
    int i = blockIdx.x * blockDim.x + threadIdx.x;
    if (i < n) { a[i] = 0; b[i] = 0; }
}

__global__ void k_hist(const int* __restrict__ dst, int* cnt) {
    int e = blockIdx.x * blockDim.x + threadIdx.x;
    if (e < N_EDGES) atomicAdd(&cnt[dst[e]], 1);
}

// per-block sums of cnt; also emit dinv = rsqrt(cnt+1)
__global__ void k_blocksum(const int* __restrict__ cnt, int* __restrict__ bsum,
                           float* __restrict__ dinv) {
    __shared__ int sdata[256];
    int t = threadIdx.x;
    int i = blockIdx.x * 256 + t;
    int v = (i < N_NODES) ? cnt[i] : 0;
    if (i < N_NODES) dinv[i] = rsqrtf((float)v + 1.0f);
    sdata[t] = v;
    __syncthreads();
    for (int s = 128; s > 0; s >>= 1) {
        if (t < s) sdata[t] += sdata[t + s];
        __syncthreads();
    }
    if (t == 0) bsum[blockIdx.x] = sdata[0];
}

// single-block exclusive scan of block sums
__global__ void k_scanbsum(const int* __restrict__ bsum, int* __restrict__ boff) {
    __shared__ int buf[256];
    int t = threadIdx.x;
    int v = (t < SCAN_NB) ? bsum[t] : 0;
    buf[t] = v;
    __syncthreads();
    for (int off = 1; off < 256; off <<= 1) {
        int a = (t >= off) ? buf[t - off] : 0;
        __syncthreads();
        buf[t] += a;
        __syncthreads();
    }
    if (t < SCAN_NB) boff[t] = buf[t] - v;   // exclusive
}

// local exclusive scan + block offset -> row
__global__ void k_localscan(const int* __restrict__ cnt, const int* __restrict__ boff,
                            int* __restrict__ row) {
    __shared__ int buf[256];
    int t = threadIdx.x;
    int i = blockIdx.x * 256 + t;
    int v = (i < N_NODES) ? cnt[i] : 0;
    buf[t] = v;
    __syncthreads();
    for (int off = 1; off < 256; off <<= 1) {
        int a = (t >= off) ? buf[t - off] : 0;
        __syncthreads();
        buf[t] += a;
        __syncthreads();
    }
    if (i < N_NODES) row[i] = boff[blockIdx.x] + buf[t] - v;
    if (i == 0) row[N_NODES] = N_EDGES;
}

// place each edge: one packed 8B store {src, norm}.
// Blocks sweep dst ranges with blockIdx%8 == range (XCD-affinity heuristic);
// correctness does not depend on the mapping.
#define FILL_GROUP_BLOCKS 392
__global__ void k_fill(const int* __restrict__ src, const int* __restrict__ dst,
                       const int* __restrict__ row, int* cur,
                       const float* __restrict__ dinv,
                       int2* __restrict__ edge) {
    int rng = blockIdx.x & 7;
    int lo = rng * (N_NODES / 8);
    int hi = (rng == 7) ? N_NODES : lo + (N_NODES / 8);
    int stride = FILL_GROUP_BLOCKS * 256;
    for (int e = (blockIdx.x >> 3) * 256 + threadIdx.x; e < N_EDGES; e += stride) {
        int d = dst[e];
        if (d < lo || d >= hi) continue;
        int s = src[e];
        int pos = atomicAdd(&cur[d], 1);
        float nm = dinv[s] * dinv[d];
        int2 packed = {s, __float_as_int(nm)};
        edge[row[d] + pos] = packed;
    }
}

// ---------------- per-layer GEMM: hw = h @ W ----------------
// 256 threads; block = 32 rows. Thread t: col-group c = t&15 (float4), rows
// rt, rt+1 (rt = (t>>4)*2). 2 rows/thread amortizes LDS W reads 2x while
// keeping the live set ~45 VGPRs (round-5's 4-row version spilled: 500MB
// FETCH of scratch traffic under the compiler's 64-VGPR occupancy cap).
__global__ __launch_bounds__(256, 4)
void k_gemm(const float* __restrict__ h, const float* __restrict__ W,
            float* __restrict__ hw) {
    __shared__ float4 Ws4[D * 16];       // 16 KB
    __shared__ float  hs[32 * 68];       // 8.7 KB, padded stride 68
    int t = threadIdx.x;
    int c = t & 15;
    int rt = (t >> 4) * 2;
    int base = blockIdx.x * 32;

    const float4* W4 = (const float4*)W;
    for (int idx = t; idx < D * 16; idx += 256) Ws4[idx] = W4[idx];
    for (int i = t; i < 32 * 16; i += 256) {
        int r = i >> 4, cc = i & 15;
        if (base + r < N_NODES)
            *(float4*)&hs[r * 68 + cc * 4] = ((const float4*)h)[(size_t)(base + r) * 16 + cc];
    }
    __syncthreads();

    float4 acc0 = {0,0,0,0}, acc1 = {0,0,0,0};
    #pragma unroll 2
    for (int kk = 0; kk < 16; ++kk) {
        float4 w0 = Ws4[(kk * 4 + 0) * 16 + c];
        float4 w1 = Ws4[(kk * 4 + 1) * 16 + c];
        float4 w2 = Ws4[(kk * 4 + 2) * 16 + c];
        float4 w3 = Ws4[(kk * 4 + 3) * 16 + c];
        float4 ha = *(const float4*)&hs[(rt + 0) * 68 + kk * 4];
        float4 hb = *(const float4*)&hs[(rt + 1) * 68 + kk * 4];
        acc0.x += ha.x * w0.x + ha.y * w1.x + ha.z * w2.x + ha.w * w3.x;
        acc0.y += ha.x * w0.y + ha.y * w1.y + ha.z * w2.y + ha.w * w3.y;
        acc0.z += ha.x * w0.z + ha.y * w1.z + ha.z * w2.z + ha.w * w3.z;
        acc0.w += ha.x * w0.w + ha.y * w1.w + ha.z * w2.w + ha.w * w3.w;
        acc1.x += hb.x * w0.x + hb.y * w1.x + hb.z * w2.x + hb.w * w3.x;
        acc1.y += hb.x * w0.y + hb.y * w1.y + hb.z * w2.y + hb.w * w3.y;
        acc1.z += hb.x * w0.z + hb.y * w1.z + hb.z * w2.z + hb.w * w3.z;
        acc1.w += hb.x * w0.w + hb.y * w1.w + hb.z * w2.w + hb.w * w3.w;
    }
    if (base + rt + 0 < N_NODES) ((float4*)hw)[(size_t)(base + rt + 0) * 16 + c] = acc0;
    if (base + rt + 1 < N_NODES) ((float4*)hw)[(size_t)(base + rt + 1) * 16 + c] = acc1;
}

// ---------------- CSR aggregate + self-loop + bias + relu ----------------
// 256 threads = 4 waves; wave = 1 node; 8 edge-subgroups x 8 lanes; each lane
// covers 2 float4 column-groups -> 16 outstanding loads per wave.
__global__ void k_aggregate(const int* __restrict__ row, const int2* __restrict__ edge,
                            const float* __restrict__ hw,
                            const float* __restrict__ dinv, const float* __restrict__ b,
                            float* __restrict__ hout) {
    int t = threadIdx.x;
    int w = t >> 6;
    int l = t & 63;
    int n = blockIdx.x * 4 + w;
    if (n >= N_NODES) return;
    int sub = l >> 3;        // 0..7: edge slot
    int c = l & 7;           // float4 col group (first half)

    const float4* hw4 = (const float4*)hw;
    float4 acc0 = {0.f, 0.f, 0.f, 0.f};
    float4 acc1 = {0.f, 0.f, 0.f, 0.f};
    int e0 = row[n], e1 = row[n + 1];
    for (int e = e0 + sub; e < e1; e += 8) {
        int2 ed = edge[e];
        int s = ed.x;
        float nm = __int_as_float(ed.y);
        float4 v0 = hw4[(size_t)s * 16 + c];
        float4 v1 = hw4[(size_t)s * 16 + c + 8];
        acc0.x += v0.x * nm; acc0.y += v0.y * nm; acc0.z += v0.z * nm; acc0.w += v0.w * nm;
        acc1.x += v1.x * nm; acc1.y += v1.y * nm; acc1.z += v1.z * nm; acc1.w += v1.w * nm;
    }
    if (sub == 0) {          // self-loop, exactly once
        float di = dinv[n];
        float sc = di * di;
        float4 v0 = hw4[(size_t)n * 16 + c];
        float4 v1 = hw4[(size_t)n * 16 + c + 8];
        acc0.x += v0.x * sc; acc0.y += v0.y * sc; acc0.z += v0.z * sc; acc0.w += v0.w * sc;
        acc1.x += v1.x * sc; acc1.y += v1.y * sc; acc1.z += v1.z * sc; acc1.w += v1.w * sc;
    }
    #pragma unroll
    for (int m = 8; m < 64; m <<= 1) {
        acc0.x += __shfl_xor(acc0.x, m); acc0.y += __shfl_xor(acc0.y, m);
        acc0.z += __shfl_xor(acc0.z, m); acc0.w += __shfl_xor(acc0.w, m);
        acc1.x += __shfl_xor(acc1.x, m); acc1.y += __shfl_xor(acc1.y, m);
        acc1.z += __shfl_xor(acc1.z, m); acc1.w += __shfl_xor(acc1.w, m);
    }

    if (sub == 0) {
        float4 b0 = ((const float4*)b)[c];
        float4 b1 = ((const float4*)b)[c + 8];
        float4 r0, r1;
        r0.x = fmaxf(acc0.x + b0.x, 0.f); r0.y = fmaxf(acc0.y + b0.y, 0.f);
        r0.z = fmaxf(acc0.z + b0.z, 0.f); r0.w = fmaxf(acc0.w + b0.w, 0.f);
        r1.x = fmaxf(acc1.x + b1.x, 0.f); r1.y = fmaxf(acc1.y + b1.y, 0.f);
        r1.z = fmaxf(acc1.z + b1.z, 0.f); r1.w = fmaxf(acc1.w + b1.w, 0.f);
        ((float4*)hout)[(size_t)n * 16 + c] = r0;
        ((float4*)hout)[(size_t)n * 16 + c + 8] = r1;
    }
}

// ---------------- pooling ----------------
__global__ void k_zero_g(float* g) {
    int i = blockIdx.x * blockDim.x + threadIdx.x;
    if (i < NUM_GRAPHS * D) g[i] = 0.f;
}

__global__ void k_pool(const int* __restrict__ batch, const float* __restrict__ h,
                       float* g) {
    int tid = blockIdx.x * blockDim.x + threadIdx.x;
    int f = tid & 63;
    int n0 = (tid >> 6) * 8;
    if (n0 >= N_NODES) return;
    int n1 = n0 + 8; if (n1 > N_NODES) n1 = N_NODES;
    int curb = batch[n0];
    float acc = 0.f;
    for (int n = n0; n < n1; ++n) {
        int bb = batch[n];
        if (bb != curb) { atomicAdd(&g[curb * D + f], acc); acc = 0.f; curb = bb; }
        acc += h[(size_t)n * D + f];
    }
    atomicAdd(&g[curb * D + f], acc);
}

// ---------------- fc1 ----------------
__global__ void k_fc1(const float* __restrict__ g, const float* __restrict__ W,
                      const float* __restrict__ b, float* __restrict__ g2) {
    int row = blockIdx.x;
    int j = threadIdx.x;
    float acc = 0.f;
    #pragma unroll
    for (int k = 0; k < D; ++k) acc += g[row * D + k] * W[k * FINAL_NEURON + j];
    acc += b[j];
    g2[row * FINAL_NEURON + j] = acc > 0.f ? acc : 0.f;
}

// ---------------- fc2 ----------------
__global__ void k_fc2(const float* __restrict__ g2, const float* __restrict__ W,
                      const float* __restrict__ b, float* __restrict__ out) {
    int row = blockIdx.x * blockDim.x + threadIdx.x;
    if (row >= NUM_GRAPHS) return;
    float acc = b[0];
    #pragma unroll
    for (int k = 0; k < FINAL_NEURON; ++k) acc += g2[row * FINAL_NEURON + k] * W[k];
    out[row] = acc;
}

extern "C" void kernel_launch(void* const* d_in, const int* in_sizes, int n_in,
                              void* d_out, int out_size, void* d_ws, size_t ws_size,
                              hipStream_t stream) {
    const float* x     = (const float*)d_in[0];
    const int*   ei    = (const int*)d_in[1];
    const int*   src   = ei;
    const int*   dst   = ei + N_EDGES;
    const int*   batch = (const int*)d_in[2];
    const float* W[5]  = {(const float*)d_in[3], (const float*)d_in[5], (const float*)d_in[7],
                          (const float*)d_in[9], (const float*)d_in[11]};
    const float* b[5]  = {(const float*)d_in[4], (const float*)d_in[6], (const float*)d_in[8],
                          (const float*)d_in[10], (const float*)d_in[12]};
    const float* fc1W  = (const float*)d_in[13];
    const float* fc1b  = (const float*)d_in[14];
    const float* fc2W  = (const float*)d_in[15];
    const float* fc2b  = (const float*)d_in[16];
    float* out = (float*)d_out;

    // ws layout: all float4-accessed arrays first (16B aligned), ints last.
    int2*  edge  = (int2*)d_ws;                     // E int2  (6.4 MB, 16B-mult)
    float* hbuf  = (float*)(edge + N_EDGES);        // N*D
    float* hw    = hbuf + (size_t)N_NODES * D;      // N*D
    float* g     = hw + (size_t)N_NODES * D;        // G*D
    float* g2    = g + NUM_GRAPHS * D;              // G*128
    float* dinv  = g2 + NUM_GRAPHS * FINAL_NEURON;  // N
    int*   cnt   = (int*)(dinv + N_NODES);          // N
    int*   row   = cnt + N_NODES;                   // N+1
    int*   cur   = row + N_NODES + 1;               // N
    int*   bsum  = cur + N_NODES;                   // 256
    int*   boff  = bsum + 256;                      // 256

    // ---- CSR build ----
    k_zero2<<<(N_NODES + 255) / 256, 256, 0, stream>>>(cnt, cur, N_NODES);
    k_hist<<<(N_EDGES + 255) / 256, 256, 0, stream>>>(dst, cnt);
    k_blocksum<<<SCAN_NB, 256, 0, stream>>>(cnt, bsum, dinv);
    k_scanbsum<<<1, 256, 0, stream>>>(bsum, boff);
    k_localscan<<<SCAN_NB, 256, 0, stream>>>(cnt, boff, row);
    k_fill<<<FILL_GROUP_BLOCKS * 8, 256, 0, stream>>>(src, dst, row, cur, dinv, edge);

    // ---- 5 GCN layers ----
    const float* hin = x;
    for (int L = 0; L < 5; ++L) {
        k_gemm<<<(N_NODES + 31) / 32, 256, 0, stream>>>(hin, W[L], hw);
        k_aggregate<<<(N_NODES + 3) / 4, 256, 0, stream>>>(row, edge, hw, dinv, b[L], hbuf);
        hin = hbuf;
    }

    // ---- readout + MLP ----
    k_zero_g<<<(NUM_GRAPHS * D + 255) / 256, 256, 0, stream>>>(g);
    k_pool<<<((N_NODES + 7) / 8 * 64 + 255) / 256, 256, 0, stream>>>(batch, hbuf, g);
    k_fc1<<<NUM_GRAPHS, FINAL_NEURON, 0, stream>>>(g, fc1W, fc1b, g2);
    k_fc2<<<(NUM_GRAPHS + 255) / 256, 256, 0, stream>>>(g2, fc2W, fc2b, out);
}

// Round 7
// 413.338 us; speedup vs baseline: 4.7111x; 1.0447x over previous
//
#include <hip/hip_runtime.h>

#define N_NODES 50000
#define N_EDGES 800000
#define D 64
#define NUM_GRAPHS 512
#define FINAL_NEURON 128
#define SCAN_NB ((N_NODES + 255) / 256)   // 196 blocks

// ---------------- CSR build ----------------
__global__ void k_zero2(int* a, int* b, int n) {
    int i = blockIdx.x * blockDim.x + threadIdx.x;
    if (i < n) { a[i] = 0; b[i] = 0; }
}

__global__ void k_hist(const int* __restrict__ dst, int* cnt) {
    int e = blockIdx.x * blockDim.x + threadIdx.x;
    if (e < N_EDGES) atomicAdd(&cnt[dst[e]], 1);
}

// per-block sums of cnt; also emit dinv = rsqrt(cnt+1); also zero g (pool acc)
__global__ void k_blocksum(const int* __restrict__ cnt, int* __restrict__ bsum,
                           float* __restrict__ dinv, float* __restrict__ g) {
    __shared__ int sdata[256];
    int t = threadIdx.x;
    int i = blockIdx.x * 256 + t;
    int v = (i < N_NODES) ? cnt[i] : 0;
    if (i < N_NODES) dinv[i] = rsqrtf((float)v + 1.0f);
    if (i < NUM_GRAPHS * D) g[i] = 0.f;          // fused g zeroing
    sdata[t] = v;
    __syncthreads();
    for (int s = 128; s > 0; s >>= 1) {
        if (t < s) sdata[t] += sdata[t + s];
        __syncthreads();
    }
    if (t == 0) bsum[blockIdx.x] = sdata[0];
}

// single-block exclusive scan of block sums
__global__ void k_scanbsum(const int* __restrict__ bsum, int* __restrict__ boff) {
    __shared__ int buf[256];
    int t = threadIdx.x;
    int v = (t < SCAN_NB) ? bsum[t] : 0;
    buf[t] = v;
    __syncthreads();
    for (int off = 1; off < 256; off <<= 1) {
        int a = (t >= off) ? buf[t - off] : 0;
        __syncthreads();
        buf[t] += a;
        __syncthreads();
    }
    if (t < SCAN_NB) boff[t] = buf[t] - v;   // exclusive
}

// local exclusive scan + block offset -> row
__global__ void k_localscan(const int* __restrict__ cnt, const int* __restrict__ boff,
                            int* __restrict__ row) {
    __shared__ int buf[256];
    int t = threadIdx.x;
    int i = blockIdx.x * 256 + t;
    int v = (i < N_NODES) ? cnt[i] : 0;
    buf[t] = v;
    __syncthreads();
    for (int off = 1; off < 256; off <<= 1) {
        int a = (t >= off) ? buf[t - off] : 0;
        __syncthreads();
        buf[t] += a;
        __syncthreads();
    }
    if (i < N_NODES) row[i] = boff[blockIdx.x] + buf[t] - v;
    if (i == 0) row[N_NODES] = N_EDGES;
}

// place each edge: one packed 8B store {src, norm}.
// Blocks sweep dst ranges with blockIdx%8 == range (XCD-affinity heuristic).
#define FILL_GROUP_BLOCKS 392
__global__ void k_fill(const int* __restrict__ src, const int* __restrict__ dst,
                       const int* __restrict__ row, int* cur,
                       const float* __restrict__ dinv,
                       int2* __restrict__ edge) {
    int rng = blockIdx.x & 7;
    int lo = rng * (N_NODES / 8);
    int hi = (rng == 7) ? N_NODES : lo + (N_NODES / 8);
    int stride = FILL_GROUP_BLOCKS * 256;
    for (int e = (blockIdx.x >> 3) * 256 + threadIdx.x; e < N_EDGES; e += stride) {
        int d = dst[e];
        if (d < lo || d >= hi) continue;
        int s = src[e];
        int pos = atomicAdd(&cur[d], 1);
        float nm = dinv[s] * dinv[d];
        int2 packed = {s, __float_as_int(nm)};
        edge[row[d] + pos] = packed;
    }
}

// ---------------- per-layer GEMM: hw = h @ W ----------------
// 256 threads; block = 32 rows; thread: 2 rows x float4. ~45 live VGPRs
// (4-row version spilled under the 64-VGPR occupancy cap — round 5).
__global__ __launch_bounds__(256, 4)
void k_gemm(const float* __restrict__ h, const float* __restrict__ W,
            float* __restrict__ hw) {
    __shared__ float4 Ws4[D * 16];       // 16 KB
    __shared__ float  hs[32 * 68];       // 8.7 KB, padded stride 68
    int t = threadIdx.x;
    int c = t & 15;
    int rt = (t >> 4) * 2;
    int base = blockIdx.x * 32;

    const float4* W4 = (const float4*)W;
    for (int idx = t; idx < D * 16; idx += 256) Ws4[idx] = W4[idx];
    for (int i = t; i < 32 * 16; i += 256) {
        int r = i >> 4, cc = i & 15;
        if (base + r < N_NODES)
            *(float4*)&hs[r * 68 + cc * 4] = ((const float4*)h)[(size_t)(base + r) * 16 + cc];
    }
    __syncthreads();

    float4 acc0 = {0,0,0,0}, acc1 = {0,0,0,0};
    #pragma unroll 2
    for (int kk = 0; kk < 16; ++kk) {
        float4 w0 = Ws4[(kk * 4 + 0) * 16 + c];
        float4 w1 = Ws4[(kk * 4 + 1) * 16 + c];
        float4 w2 = Ws4[(kk * 4 + 2) * 16 + c];
        float4 w3 = Ws4[(kk * 4 + 3) * 16 + c];
        float4 ha = *(const float4*)&hs[(rt + 0) * 68 + kk * 4];
        float4 hb = *(const float4*)&hs[(rt + 1) * 68 + kk * 4];
        acc0.x += ha.x * w0.x + ha.y * w1.x + ha.z * w2.x + ha.w * w3.x;
        acc0.y += ha.x * w0.y + ha.y * w1.y + ha.z * w2.y + ha.w * w3.y;
        acc0.z += ha.x * w0.z + ha.y * w1.z + ha.z * w2.z + ha.w * w3.z;
        acc0.w += ha.x * w0.w + ha.y * w1.w + ha.z * w2.w + ha.w * w3.w;
        acc1.x += hb.x * w0.x + hb.y * w1.x + hb.z * w2.x + hb.w * w3.x;
        acc1.y += hb.x * w0.y + hb.y * w1.y + hb.z * w2.y + hb.w * w3.y;
        acc1.z += hb.x * w0.z + hb.y * w1.z + hb.z * w2.z + hb.w * w3.z;
        acc1.w += hb.x * w0.w + hb.y * w1.w + hb.z * w2.w + hb.w * w3.w;
    }
    if (base + rt + 0 < N_NODES) ((float4*)hw)[(size_t)(base + rt + 0) * 16 + c] = acc0;
    if (base + rt + 1 < N_NODES) ((float4*)hw)[(size_t)(base + rt + 1) * 16 + c] = acc1;
}

// ---------------- CSR aggregate + self-loop + bias + relu ----------------
// 16 lanes per node (4 nodes/wave, 16 nodes/block). Each lane owns one float4
// column of the row: no shuffles, no idle lanes, edge loop unrolled x2.
// N_NODES = 3125 * 16 exactly -> no bounds checks.
__global__ __launch_bounds__(256, 8)
void k_aggregate(const int* __restrict__ row, const int2* __restrict__ edge,
                 const float* __restrict__ hw,
                 const float* __restrict__ dinv, const float* __restrict__ b,
                 float* __restrict__ hout) {
    int t = threadIdx.x;
    int c = t & 15;                       // float4 col group
    int n = blockIdx.x * 16 + (t >> 4);   // node

    const float4* hw4 = (const float4*)hw;
    float4 acc = {0.f, 0.f, 0.f, 0.f};
    int e = row[n], e1 = row[n + 1];
    for (; e + 2 <= e1; e += 2) {
        int2 ed0 = edge[e];
        int2 ed1 = edge[e + 1];
        float4 v0 = hw4[(size_t)ed0.x * 16 + c];
        float4 v1 = hw4[(size_t)ed1.x * 16 + c];
        float n0 = __int_as_float(ed0.y);
        float n1 = __int_as_float(ed1.y);
        acc.x += v0.x * n0 + v1.x * n1;
        acc.y += v0.y * n0 + v1.y * n1;
        acc.z += v0.z * n0 + v1.z * n1;
        acc.w += v0.w * n0 + v1.w * n1;
    }
    if (e < e1) {
        int2 ed = edge[e];
        float nm = __int_as_float(ed.y);
        float4 v = hw4[(size_t)ed.x * 16 + c];
        acc.x += v.x * nm; acc.y += v.y * nm; acc.z += v.z * nm; acc.w += v.w * nm;
    }
    // self-loop
    float di = dinv[n];
    float sc = di * di;
    float4 vs = hw4[(size_t)n * 16 + c];
    acc.x += vs.x * sc; acc.y += vs.y * sc; acc.z += vs.z * sc; acc.w += vs.w * sc;

    float4 bb = ((const float4*)b)[c];
    float4 r;
    r.x = fmaxf(acc.x + bb.x, 0.f);
    r.y = fmaxf(acc.y + bb.y, 0.f);
    r.z = fmaxf(acc.z + bb.z, 0.f);
    r.w = fmaxf(acc.w + bb.w, 0.f);
    ((float4*)hout)[(size_t)n * 16 + c] = r;
}

// ---------------- pooling ----------------
__global__ void k_pool(const int* __restrict__ batch, const float* __restrict__ h,
                       float* g) {
    int tid = blockIdx.x * blockDim.x + threadIdx.x;
    int f = tid & 63;
    int n0 = (tid >> 6) * 8;
    if (n0 >= N_NODES) return;
    int n1 = n0 + 8; if (n1 > N_NODES) n1 = N_NODES;
    int curb = batch[n0];
    float acc = 0.f;
    for (int n = n0; n < n1; ++n) {
        int bb = batch[n];
        if (bb != curb) { atomicAdd(&g[curb * D + f], acc); acc = 0.f; curb = bb; }
        acc += h[(size_t)n * D + f];
    }
    atomicAdd(&g[curb * D + f], acc);
}

// ---------------- fused MLP: out[row] = fc2(relu(fc1(g[row]))) ----------------
__global__ void k_mlp(const float* __restrict__ g, const float* __restrict__ W1,
                      const float* __restrict__ b1, const float* __restrict__ W2,
                      const float* __restrict__ b2, float* __restrict__ out) {
    __shared__ float red[FINAL_NEURON];
    int row = blockIdx.x;
    int j = threadIdx.x;
    float acc = 0.f;
    #pragma unroll
    for (int k = 0; k < D; ++k) acc += g[row * D + k] * W1[k * FINAL_NEURON + j];
    acc = fmaxf(acc + b1[j], 0.f);
    red[j] = acc * W2[j];
    __syncthreads();
    for (int s = 64; s > 0; s >>= 1) {
        if (j < s) red[j] += red[j + s];
        __syncthreads();
    }
    if (j == 0) out[row] = red[0] + b2[0];
}

extern "C" void kernel_launch(void* const* d_in, const int* in_sizes, int n_in,
                              void* d_out, int out_size, void* d_ws, size_t ws_size,
                              hipStream_t stream) {
    const float* x     = (const float*)d_in[0];
    const int*   ei    = (const int*)d_in[1];
    const int*   src   = ei;
    const int*   dst   = ei + N_EDGES;
    const int*   batch = (const int*)d_in[2];
    const float* W[5]  = {(const float*)d_in[3], (const float*)d_in[5], (const float*)d_in[7],
                          (const float*)d_in[9], (const float*)d_in[11]};
    const float* b[5]  = {(const float*)d_in[4], (const float*)d_in[6], (const float*)d_in[8],
                          (const float*)d_in[10], (const float*)d_in[12]};
    const float* fc1W  = (const float*)d_in[13];
    const float* fc1b  = (const float*)d_in[14];
    const float* fc2W  = (const float*)d_in[15];
    const float* fc2b  = (const float*)d_in[16];
    float* out = (float*)d_out;

    // ws layout: float4-accessed arrays first (16B aligned), ints last.
    int2*  edge  = (int2*)d_ws;                     // E int2
    float* hbuf  = (float*)(edge + N_EDGES);        // N*D
    float* hw    = hbuf + (size_t)N_NODES * D;      // N*D
    float* g     = hw + (size_t)N_NODES * D;        // G*D
    float* dinv  = g + NUM_GRAPHS * D;              // N
    int*   cnt   = (int*)(dinv + N_NODES);          // N
    int*   row   = cnt + N_NODES;                   // N+1
    int*   cur   = row + N_NODES + 1;               // N
    int*   bsum  = cur + N_NODES;                   // 256
    int*   boff  = bsum + 256;                      // 256

    // ---- CSR build ----
    k_zero2<<<(N_NODES + 255) / 256, 256, 0, stream>>>(cnt, cur, N_NODES);
    k_hist<<<(N_EDGES + 255) / 256, 256, 0, stream>>>(dst, cnt);
    k_blocksum<<<SCAN_NB, 256, 0, stream>>>(cnt, bsum, dinv, g);
    k_scanbsum<<<1, 256, 0, stream>>>(bsum, boff);
    k_localscan<<<SCAN_NB, 256, 0, stream>>>(cnt, boff, row);
    k_fill<<<FILL_GROUP_BLOCKS * 8, 256, 0, stream>>>(src, dst, row, cur, dinv, edge);

    // ---- 5 GCN layers ----
    const float* hin = x;
    for (int L = 0; L < 5; ++L) {
        k_gemm<<<(N_NODES + 31) / 32, 256, 0, stream>>>(hin, W[L], hw);
        k_aggregate<<<N_NODES / 16, 256, 0, stream>>>(row, edge, hw, dinv, b[L], hbuf);
        hin = hbuf;
    }

    // ---- readout + fused MLP ----
    k_pool<<<((N_NODES + 7) / 8 * 64 + 255) / 256, 256, 0, stream>>>(batch, hbuf, g);
    k_mlp<<<NUM_GRAPHS, FINAL_NEURON, 0, stream>>>(g, fc1W, fc1b, fc2W, fc2b, out);
}